// Round 5
// baseline (308.913 us; speedup 1.0000x reference)
//
#include <hip/hip_runtime.h>

// Problem constants (fixed by setup_inputs)
#define B_   8
#define NN   2000
#define EE   20
#define HH   128
#define BN   (B_*NN)      // 16000 rows of x
#define NE   (NN*EE)      // 40000 e-rows per batch

typedef unsigned short ushort_t;
typedef __bf16 bf16x8 __attribute__((ext_vector_type(8)));
typedef float  f32x4  __attribute__((ext_vector_type(4)));
typedef float  f4     __attribute__((ext_vector_type(4)));
typedef unsigned short us8 __attribute__((ext_vector_type(8)));
typedef unsigned short us4 __attribute__((ext_vector_type(4)));

union FragU { us8 u; bf16x8 b; };

__device__ __forceinline__ float b2f(ushort_t v) {
    union { unsigned int i; float f; } c; c.i = ((unsigned int)v) << 16; return c.f;
}
__device__ __forceinline__ ushort_t f2b(float f) {   // RNE fp32 -> bf16
    union { float f; unsigned int i; } c; c.f = f;
    unsigned int r = (c.i + 0x7FFFu + ((c.i >> 16) & 1u)) >> 16;
    return (ushort_t)r;
}

// ---------------------------------------------------------------------------
// K0: WT = bf16(W^T) for Wu, Wv, We (so every MFMA B-frag is one us8 load).
// 3 blocks; LDS transpose so global read AND write are coalesced.
// ---------------------------------------------------------------------------
__global__ __launch_bounds__(256) void k0_prep(
    const float* __restrict__ Wu, const float* __restrict__ Wv,
    const float* __restrict__ We,
    ushort_t* __restrict__ WuT, ushort_t* __restrict__ WvT,
    ushort_t* __restrict__ WeT)
{
    __shared__ ushort_t lds[128 * 130];
    const int bid = blockIdx.x;
    const float* W = (bid == 0) ? Wu : (bid == 1) ? Wv : We;
    ushort_t*   WT = (bid == 0) ? WuT : (bid == 1) ? WvT : WeT;
#pragma unroll
    for (int it = 0; it < 64; ++it) {
        int c = it * 256 + threadIdx.x;            // c = k*128 + n (coalesced read)
        lds[(c >> 7) * 130 + (c & 127)] = f2b(W[c]);
    }
    __syncthreads();
#pragma unroll
    for (int it = 0; it < 64; ++it) {
        int o = it * 256 + threadIdx.x;            // o = n*128 + k (coalesced write)
        WT[o] = lds[(o & 127) * 130 + (o >> 7)];
    }
}

// ---------------------------------------------------------------------------
// K1: Uxb = bf16(x@Wu + bu), Vxb = bf16(x@Wv + bv)   (both -> ws)
// Barrier-free. A streamed per-ki directly from x (fp32->bf16 in regs);
// B-frags are single us8 loads from WT. grid (250, 2); 4 waves (2x2).
// ---------------------------------------------------------------------------
__global__ __launch_bounds__(256, 4) void k1_embed(
    const float* __restrict__ x,
    const ushort_t* __restrict__ WuT, const float* __restrict__ bu,
    const ushort_t* __restrict__ WvT, const float* __restrict__ bv,
    ushort_t* __restrict__ Uxb, ushort_t* __restrict__ Vxb)
{
    const int tid  = threadIdx.x;
    const int lane = tid & 63;
    const int wave = tid >> 6;
    const int wm = wave >> 1, wn = wave & 1;
    const int q  = lane >> 4, ln = lane & 15;
    const int m0 = blockIdx.x * 64;
    const int sel = blockIdx.y;
    const ushort_t* WT   = sel ? WvT : WuT;
    const float*    bias = sel ? bv : bu;
    ushort_t* dst = sel ? Vxb : Uxb;

    // B fragments: one us8 (16B) coalesced load each
    FragU bf[4][4];  // [ki][tn]
#pragma unroll
    for (int ki = 0; ki < 4; ++ki)
#pragma unroll
        for (int tn = 0; tn < 4; ++tn)
            bf[ki][tn].u = *(const us8*)(WT + (size_t)(wn * 64 + tn * 16 + ln) * HH + ki * 32 + q * 8);

    f32x4 acc[2][4];
#pragma unroll
    for (int tm = 0; tm < 2; ++tm)
#pragma unroll
        for (int tn = 0; tn < 4; ++tn) acc[tm][tn] = (f32x4){0.f, 0.f, 0.f, 0.f};

#pragma unroll
    for (int ki = 0; ki < 4; ++ki) {
        FragU af[2];
#pragma unroll
        for (int tm = 0; tm < 2; ++tm) {
            const float* p = x + (size_t)(m0 + wm * 32 + tm * 16 + ln) * HH + ki * 32 + q * 8;
            f4 lo = *(const f4*)(p);
            f4 hi = *(const f4*)(p + 4);
            us8 t;
#pragma unroll
            for (int r = 0; r < 4; ++r) { t[r] = f2b(lo[r]); t[r + 4] = f2b(hi[r]); }
            af[tm].u = t;
        }
#pragma unroll
        for (int tm = 0; tm < 2; ++tm)
#pragma unroll
            for (int tn = 0; tn < 4; ++tn)
                acc[tm][tn] = __builtin_amdgcn_mfma_f32_16x16x32_bf16(
                    af[tm].b, bf[ki][tn].b, acc[tm][tn], 0, 0, 0);
    }

    // D layout: col=lane&15, row=(lane>>4)*4+reg
#pragma unroll
    for (int tn = 0; tn < 4; ++tn) {
        int col = wn * 64 + tn * 16 + ln;
        float bb = bias[col];
#pragma unroll
        for (int tm = 0; tm < 2; ++tm) {
            int rowb = m0 + wm * 32 + tm * 16 + q * 4;
#pragma unroll
            for (int r = 0; r < 4; ++r)
                dst[(size_t)(rowb + r) * HH + col] = f2b(acc[tm][tn][r] + bb);
        }
    }
}

// ---------------------------------------------------------------------------
// K2: ZERO-BARRIER. per block = 4 nodes (80 e-rows), grid (500, 8).
// Each wave owns cols [wave*32, wave*32+32):
//   - A-frags loaded DIRECTLY from e (fp32->bf16 in regs); per-(tm,ki) the
//     wave's lanes cover 16 full 128B lines (perfect coalescing). The 4x
//     intra-block redundancy is L1/L2-absorbed; HBM traffic unchanged.
//   - logits -> CT slice in LDS (wave-local write->read, lgkmcnt orders it)
//   - softmax over E=20, eidx loaded per-lane from global (L2-hot),
//     gather Vxb, weighted sum, + Uxb -> out fp32.
// be cancels in softmax -> skipped.
// ---------------------------------------------------------------------------
#define CSTR 84    // CT stride (ushorts)

__global__ __launch_bounds__(256, 4) void k2_fused(
    const float* __restrict__ e, const ushort_t* __restrict__ WeT,
    const int* __restrict__ eidx,
    const ushort_t* __restrict__ Uxb, const ushort_t* __restrict__ Vxb,
    float* __restrict__ out)
{
    __shared__ __align__(16) ushort_t ct[128 * CSTR];   // 21504 B

    const int tid  = threadIdx.x;
    const int lane = tid & 63;
    const int wave = tid >> 6;            // owns cols [wave*32, wave*32+32)
    const int q  = lane >> 4, ln = lane & 15;

    const int b   = blockIdx.y;
    const int nl0 = blockIdx.x * 4;       // first node (local)
    const size_t erow0 = (size_t)b * NE + (size_t)nl0 * EE;  // 80 rows
    const float* ebase = e + erow0 * HH;

    // B fragments: one us8 each from WeT (L2-hot)
    FragU bf[4][2];  // [ki][tn]
#pragma unroll
    for (int ki = 0; ki < 4; ++ki)
#pragma unroll
        for (int tn = 0; tn < 2; ++tn)
            bf[ki][tn].u = *(const us8*)(WeT + (size_t)(wave * 32 + tn * 16 + ln) * HH + ki * 32 + q * 8);

    f32x4 acc[5][2];
#pragma unroll
    for (int tm = 0; tm < 5; ++tm)
#pragma unroll
        for (int tn = 0; tn < 2; ++tn) acc[tm][tn] = (f32x4){0.f, 0.f, 0.f, 0.f};

#pragma unroll
    for (int ki = 0; ki < 4; ++ki) {
        FragU af[5];
#pragma unroll
        for (int tm = 0; tm < 5; ++tm) {
            const float* p = ebase + (size_t)(tm * 16 + ln) * HH + ki * 32 + q * 8;
            f4 lo = *(const f4*)(p);
            f4 hi = *(const f4*)(p + 4);
            us8 t;
#pragma unroll
            for (int r = 0; r < 4; ++r) { t[r] = f2b(lo[r]); t[r + 4] = f2b(hi[r]); }
            af[tm].u = t;
        }
#pragma unroll
        for (int tm = 0; tm < 5; ++tm)
#pragma unroll
            for (int tn = 0; tn < 2; ++tn)
                acc[tm][tn] = __builtin_amdgcn_mfma_f32_16x16x32_bf16(
                    af[tm].b, bf[ki][tn].b, acc[tm][tn], 0, 0, 0);
    }

    // CT[col][row] bf16 (own slice): lane's 4 regs = 4 consecutive rows -> us4
#pragma unroll
    for (int tm = 0; tm < 5; ++tm)
#pragma unroll
        for (int tn = 0; tn < 2; ++tn) {
            int col  = wave * 32 + tn * 16 + ln;
            int rowb = tm * 16 + q * 4;
            us4 pk;
#pragma unroll
            for (int r = 0; r < 4; ++r) pk[r] = f2b(acc[tm][tn][r]);
            *(us4*)(&ct[col * CSTR + rowb]) = pk;
        }

    // epilogue (no barrier: reads only this wave's CT slice)
    const int hh = lane & 31;
    const int gh = lane >> 5;             // 0 or 1
    const int h  = wave * 32 + hh;
    const ushort_t* vbase = Vxb + (size_t)b * NN * HH + h;
    const int* ebidx = eidx + erow0;
#pragma unroll
    for (int j = 0; j < 2; ++j) {
        int g = gh + 2 * j;
        const ushort_t* ctp = &ct[h * CSTR + g * 20];
        float lv[20];
#pragma unroll
        for (int i = 0; i < 5; ++i) {
            us4 v = *(const us4*)(ctp + i * 4);
#pragma unroll
            for (int r = 0; r < 4; ++r) lv[i * 4 + r] = b2f(v[r]);
        }
        float mx = lv[0];
#pragma unroll
        for (int k = 1; k < EE; ++k) mx = fmaxf(mx, lv[k]);

        // indices first (independent loads), then gathers (all in flight)
        int idx[20];
#pragma unroll
        for (int k = 0; k < EE; ++k) idx[k] = ebidx[g * 20 + k];
        ushort_t gv[20];
#pragma unroll
        for (int k = 0; k < EE; ++k) gv[k] = vbase[(size_t)idx[k] * HH];

        float s = 0.f, a = 0.f;
#pragma unroll
        for (int k = 0; k < EE; ++k) {
            float p = __expf(lv[k] - mx);
            s += p;
            a = fmaf(p, b2f(gv[k]), a);
        }
        size_t orow = (size_t)(b * NN + nl0 + g) * HH + h;
        out[orow] = b2f(Uxb[orow]) + a / s;
    }
}

// ---------------------------------------------------------------------------
extern "C" void kernel_launch(void* const* d_in, const int* in_sizes, int n_in,
                              void* d_out, int out_size, void* d_ws, size_t ws_size,
                              hipStream_t stream) {
    const float* x  = (const float*)d_in[0];
    const float* e  = (const float*)d_in[1];
    const float* Wu = (const float*)d_in[2];
    const float* bu = (const float*)d_in[3];
    const float* Wv = (const float*)d_in[4];
    const float* bv = (const float*)d_in[5];
    const float* We = (const float*)d_in[6];
    // d_in[7] = be: cancels in softmax, unused
    const int*   eidx = (const int*)d_in[8];
    // d_in[9] = n_edges (=20), compiled in

    const size_t SZ = (size_t)BN * HH * 2;            // 4.096 MB per bf16 buffer
    ushort_t* Uxb = (ushort_t*)d_ws;
    ushort_t* Vxb = (ushort_t*)((char*)d_ws + SZ);
    ushort_t* WuT = (ushort_t*)((char*)d_ws + 2 * SZ);
    ushort_t* WvT = WuT + HH * HH;
    ushort_t* WeT = WvT + HH * HH;
    float*    o   = (float*)d_out;

    k0_prep<<<dim3(3), 256, 0, stream>>>(Wu, Wv, We, WuT, WvT, WeT);
    k1_embed<<<dim3(250, 2), 256, 0, stream>>>(x, WuT, bu, WvT, bv, Uxb, Vxb);
    k2_fused<<<dim3(500, 8), 256, 0, stream>>>(e, WeT, eidx, Uxb, Vxb, o);
}

// Round 6
// 276.937 us; speedup vs baseline: 1.1155x; 1.1155x over previous
//
#include <hip/hip_runtime.h>

// Problem constants (fixed by setup_inputs)
#define B_   8
#define NN   2000
#define EE   20
#define HH   128
#define BN   (B_*NN)      // 16000 rows of x
#define NE   (NN*EE)      // 40000 e-rows per batch

typedef unsigned short ushort_t;
typedef __bf16 bf16x8 __attribute__((ext_vector_type(8)));
typedef float  f32x4  __attribute__((ext_vector_type(4)));
typedef float  f4     __attribute__((ext_vector_type(4)));
typedef unsigned short us8 __attribute__((ext_vector_type(8)));
typedef unsigned short us4 __attribute__((ext_vector_type(4)));

union FragU { us8 u; bf16x8 b; };

__device__ __forceinline__ float b2f(ushort_t v) {
    union { unsigned int i; float f; } c; c.i = ((unsigned int)v) << 16; return c.f;
}
__device__ __forceinline__ ushort_t f2b(float f) {   // RNE fp32 -> bf16
    union { float f; unsigned int i; } c; c.f = f;
    unsigned int r = (c.i + 0x7FFFu + ((c.i >> 16) & 1u)) >> 16;
    return (ushort_t)r;
}

// ---------------------------------------------------------------------------
// K0: WT = bf16(W^T) for Wu, Wv, We (so every MFMA B-frag is one us8 load).
// 3 blocks; LDS transpose so global read AND write are coalesced.
// ---------------------------------------------------------------------------
__global__ __launch_bounds__(256) void k0_prep(
    const float* __restrict__ Wu, const float* __restrict__ Wv,
    const float* __restrict__ We,
    ushort_t* __restrict__ WuT, ushort_t* __restrict__ WvT,
    ushort_t* __restrict__ WeT)
{
    __shared__ ushort_t lds[128 * 130];
    const int bid = blockIdx.x;
    const float* W = (bid == 0) ? Wu : (bid == 1) ? Wv : We;
    ushort_t*   WT = (bid == 0) ? WuT : (bid == 1) ? WvT : WeT;
#pragma unroll
    for (int it = 0; it < 64; ++it) {
        int c = it * 256 + threadIdx.x;            // c = k*128 + n (coalesced read)
        lds[(c >> 7) * 130 + (c & 127)] = f2b(W[c]);
    }
    __syncthreads();
#pragma unroll
    for (int it = 0; it < 64; ++it) {
        int o = it * 256 + threadIdx.x;            // o = n*128 + k (coalesced write)
        WT[o] = lds[(o & 127) * 130 + (o >> 7)];
    }
}

// ---------------------------------------------------------------------------
// K1: Uxb = bf16(x@Wu + bu), Vxb = bf16(x@Wv + bv)   (both -> ws)
// 16-row tiles, grid (1000, 2) -> ~8 blocks/CU. Barrier-free.
// 4 waves/block; wave w owns cols [w*32, w*32+32) (2 n-tiles).
// A streamed per-ki from x (fp32->bf16 in regs); B = one us8 per frag.
// ---------------------------------------------------------------------------
__global__ __launch_bounds__(256, 8) void k1_embed(
    const float* __restrict__ x,
    const ushort_t* __restrict__ WuT, const float* __restrict__ bu,
    const ushort_t* __restrict__ WvT, const float* __restrict__ bv,
    ushort_t* __restrict__ Uxb, ushort_t* __restrict__ Vxb)
{
    const int tid  = threadIdx.x;
    const int lane = tid & 63;
    const int w    = tid >> 6;
    const int q  = lane >> 4, ln = lane & 15;
    const int m0 = blockIdx.x * 16;
    const int sel = blockIdx.y;
    const ushort_t* WT   = sel ? WvT : WuT;
    const float*    bias = sel ? bv : bu;
    ushort_t* dst = sel ? Vxb : Uxb;

    f32x4 acc[2];
    acc[0] = (f32x4){0.f, 0.f, 0.f, 0.f};
    acc[1] = (f32x4){0.f, 0.f, 0.f, 0.f};

#pragma unroll
    for (int ki = 0; ki < 4; ++ki) {
        // A frag: row m0+ln, cols ki*32+q*8..+8 (16 rows x 32 cols per wave)
        const float* p = x + (size_t)(m0 + ln) * HH + ki * 32 + q * 8;
        f4 lo = *(const f4*)(p);
        f4 hi = *(const f4*)(p + 4);
        FragU af;
        us8 t;
#pragma unroll
        for (int r = 0; r < 4; ++r) { t[r] = f2b(lo[r]); t[r + 4] = f2b(hi[r]); }
        af.u = t;
        FragU bf0, bf1;
        bf0.u = *(const us8*)(WT + (size_t)(w * 32 + ln) * HH + ki * 32 + q * 8);
        bf1.u = *(const us8*)(WT + (size_t)(w * 32 + 16 + ln) * HH + ki * 32 + q * 8);
        acc[0] = __builtin_amdgcn_mfma_f32_16x16x32_bf16(af.b, bf0.b, acc[0], 0, 0, 0);
        acc[1] = __builtin_amdgcn_mfma_f32_16x16x32_bf16(af.b, bf1.b, acc[1], 0, 0, 0);
    }

    // D layout: col=lane&15, row=(lane>>4)*4+reg
#pragma unroll
    for (int tn = 0; tn < 2; ++tn) {
        int col = w * 32 + tn * 16 + ln;
        float bb = bias[col];
#pragma unroll
        for (int r = 0; r < 4; ++r)
            dst[(size_t)(m0 + q * 4 + r) * HH + col] = f2b(acc[tn][r] + bb);
    }
}

// ---------------------------------------------------------------------------
// K2: per block = 4 nodes (80 e-rows), 512 threads / 8 waves, grid (500, 8).
// Wave w owns n-tile w (cols [w*16, w*16+16)).
//   stage A once (fp32->bf16) -> LDS [80 x 136]   (barrier 1)
//   MFMA: per ki: 5 ds_read_b128 A-frags + 1 us8 B-frag (L1-hot) -> acc[5]
//   (barrier 2) -> CT slice [col*84 + row] (wave-local, us4 stores)
//   epilogue: exactly 1 (node g, channel h) per lane; softmax over E=20,
//   gather Vxb, + Uxb -> out fp32.  No 3rd barrier (wave-local CT).
// be cancels in softmax -> skipped.  ~4 blocks/CU (100% occupancy target).
// ---------------------------------------------------------------------------
#define ASTR 136   // A stride (ushorts)
#define CSTR 84    // CT stride (ushorts)

__global__ __launch_bounds__(512, 8) void k2_fused(
    const float* __restrict__ e, const ushort_t* __restrict__ WeT,
    const int* __restrict__ eidx,
    const ushort_t* __restrict__ Uxb, const ushort_t* __restrict__ Vxb,
    float* __restrict__ out)
{
    __shared__ __align__(16) ushort_t smem[80 * ASTR];  // 21760 B; CT (128*84) aliases

    const int tid  = threadIdx.x;
    const int lane = tid & 63;
    const int w    = tid >> 6;            // 8 waves; wave w owns cols [w*16, w*16+16)
    const int q  = lane >> 4, ln = lane & 15;

    const int b   = blockIdx.y;
    const int nl0 = blockIdx.x * 4;       // first node (local)
    const size_t erow0 = (size_t)b * NE + (size_t)nl0 * EE;  // 80 rows
    const float* ebase = e + erow0 * HH;

    // stage A: 80 rows x 128 cols fp32 -> bf16 (each element exactly once)
#pragma unroll
    for (int it = 0; it < 5; ++it) {
        int c = it * 512 + tid;           // c in [0, 2560)
        int row = c >> 5, col = (c & 31) * 4;
        f4 v = *(const f4*)(ebase + (size_t)row * HH + col);
        us4 pk;
#pragma unroll
        for (int r = 0; r < 4; ++r) pk[r] = f2b(v[r]);
        *(us4*)(&smem[row * ASTR + col]) = pk;
    }

    f32x4 acc[5];
#pragma unroll
    for (int tm = 0; tm < 5; ++tm) acc[tm] = (f32x4){0.f, 0.f, 0.f, 0.f};

    __syncthreads();   // barrier 1: A staged

#pragma unroll
    for (int ki = 0; ki < 4; ++ki) {
        FragU bf;      // B reloaded per-ki: keeps VGPR low; WeT is L1-hot
        bf.u = *(const us8*)(WeT + (size_t)(w * 16 + ln) * HH + ki * 32 + q * 8);
        FragU af[5];
#pragma unroll
        for (int tm = 0; tm < 5; ++tm)
            af[tm].u = *(const us8*)(&smem[(tm * 16 + ln) * ASTR + ki * 32 + q * 8]);
#pragma unroll
        for (int tm = 0; tm < 5; ++tm)
            acc[tm] = __builtin_amdgcn_mfma_f32_16x16x32_bf16(af[tm].b, bf.b, acc[tm], 0, 0, 0);
    }

    __syncthreads();   // barrier 2: all A reads done; smem becomes CT

    // CT[col*CSTR + row] (own 16-col slice): lane's 4 regs = 4 consecutive rows
    {
        int col = w * 16 + ln;
#pragma unroll
        for (int tm = 0; tm < 5; ++tm) {
            us4 pk;
#pragma unroll
            for (int r = 0; r < 4; ++r) pk[r] = f2b(acc[tm][r]);
            *(us4*)(&smem[col * CSTR + tm * 16 + q * 4]) = pk;
        }
    }

    // epilogue: 1 item/lane. g = lane>>4 (node), h = w*16 + (lane&15) (channel)
    const int g = lane >> 4;
    const int h = w * 16 + ln;
    const int* ebidx = eidx + erow0 + g * EE;
    const ushort_t* vbase = Vxb + (size_t)b * NN * HH + h;

    float lv[20];
    {
        const ushort_t* ctp = &smem[h * CSTR + g * EE];
#pragma unroll
        for (int i = 0; i < 5; ++i) {
            us4 v = *(const us4*)(ctp + i * 4);
#pragma unroll
            for (int r = 0; r < 4; ++r) lv[i * 4 + r] = b2f(v[r]);
        }
    }
    float mx = lv[0];
#pragma unroll
    for (int k = 1; k < EE; ++k) mx = fmaxf(mx, lv[k]);

    float s = 0.f, a = 0.f;
#pragma unroll
    for (int half = 0; half < 2; ++half) {   // batches of 10: bounds VGPRs
        int idx[10];
#pragma unroll
        for (int k = 0; k < 10; ++k) idx[k] = ebidx[half * 10 + k];
        ushort_t gv[10];
#pragma unroll
        for (int k = 0; k < 10; ++k) gv[k] = vbase[(size_t)idx[k] * HH];
#pragma unroll
        for (int k = 0; k < 10; ++k) {
            float p = __expf(lv[half * 10 + k] - mx);
            s += p;
            a = fmaf(p, b2f(gv[k]), a);
        }
    }
    size_t orow = (size_t)(b * NN + nl0 + g) * HH + h;
    out[orow] = b2f(Uxb[orow]) + a / s;
}

// ---------------------------------------------------------------------------
extern "C" void kernel_launch(void* const* d_in, const int* in_sizes, int n_in,
                              void* d_out, int out_size, void* d_ws, size_t ws_size,
                              hipStream_t stream) {
    const float* x  = (const float*)d_in[0];
    const float* e  = (const float*)d_in[1];
    const float* Wu = (const float*)d_in[2];
    const float* bu = (const float*)d_in[3];
    const float* Wv = (const float*)d_in[4];
    const float* bv = (const float*)d_in[5];
    const float* We = (const float*)d_in[6];
    // d_in[7] = be: cancels in softmax, unused
    const int*   eidx = (const int*)d_in[8];
    // d_in[9] = n_edges (=20), compiled in

    const size_t SZ = (size_t)BN * HH * 2;            // 4.096 MB per bf16 buffer
    ushort_t* Uxb = (ushort_t*)d_ws;
    ushort_t* Vxb = (ushort_t*)((char*)d_ws + SZ);
    ushort_t* WuT = (ushort_t*)((char*)d_ws + 2 * SZ);
    ushort_t* WvT = WuT + HH * HH;
    ushort_t* WeT = WvT + HH * HH;
    float*    o   = (float*)d_out;

    k0_prep<<<dim3(3), 256, 0, stream>>>(Wu, Wv, We, WuT, WvT, WeT);
    k1_embed<<<dim3(1000, 2), 256, 0, stream>>>(x, WuT, bu, WvT, bv, Uxb, Vxb);
    k2_fused<<<dim3(500, 8), 512, 0, stream>>>(e, WeT, eidx, Uxb, Vxb, o);
}